// Round 3
// baseline (1078.562 us; speedup 1.0000x reference)
//
#include <hip/hip_runtime.h>
#include <hip/hip_bf16.h>
#include <cstdint>
#include <cstddef>

#define B_ 128
#define S_ 256
#define TOK (B_*S_)   // 32768

typedef __bf16 bf16x8 __attribute__((ext_vector_type(8)));
typedef float  f32x4  __attribute__((ext_vector_type(4)));

__device__ __forceinline__ float sigf(float x) {
    return __builtin_amdgcn_rcpf(1.0f + __expf(-x));
}
__device__ __forceinline__ float tanhfast(float x) {
    return 1.0f - 2.0f * __builtin_amdgcn_rcpf(1.0f + __expf(2.0f * x));
}
__device__ __forceinline__ float bf2f(unsigned short v) {
    union { unsigned u; float f; } c; c.u = ((unsigned)v) << 16; return c.f;
}

// ---- K1: char input-gate table: gin[dir][c][row] = b[row] + Wih[row,:]·emb[c,:]
__global__ void k_gin(const float* __restrict__ ce,
                      const float* __restrict__ wih_f, const float* __restrict__ b_f,
                      const float* __restrict__ wih_b, const float* __restrict__ b_b,
                      float* __restrict__ gin) {
    int tid = blockIdx.x * blockDim.x + threadIdx.x;
    if (tid >= 200) return;
    int dir = tid / 100, row = tid % 100;
    const float* wih = dir ? wih_b : wih_f;
    float bias = dir ? b_b[row] : b_f[row];
    for (int c = 0; c < 100; ++c) {
        float s = bias;
#pragma unroll
        for (int k = 0; k < 25; ++k) s += wih[row*25 + k] * ce[c*25 + k];
        gin[(dir*100 + c)*100 + row] = s;
    }
}

// ---- K1b: combined word-input weight [800][152] (k-padded) + bias [800]
__global__ void k_wcomb(const float* __restrict__ wih_f, const float* __restrict__ bf,
                        const float* __restrict__ wih_b, const float* __restrict__ bb,
                        float* __restrict__ Wc, float* __restrict__ bc) {
    int idx = blockIdx.x * blockDim.x + threadIdx.x;
    if (idx < 800*152) {
        int n = idx / 152, k = idx - n*152;
        int dir = n >= 400 ? 1 : 0, r = n - dir*400;
        const float* w = dir ? wih_b : wih_f;
        Wc[idx] = (k < 150) ? w[r*150 + k] : 0.0f;
    }
    if (idx < 800) {
        int dir = idx >= 400 ? 1 : 0, r = idx - dir*400;
        bc[idx] = dir ? bb[r] : bf[r];
    }
}

// ---- K1c: pad char Whh into [dir][gate][k=25][28] (f32, zeros past j=25).
__global__ void k_wpad(const float* __restrict__ whh_f, const float* __restrict__ whh_b,
                       float* __restrict__ wpad) {
    int idx = blockIdx.x * blockDim.x + threadIdx.x;
    if (idx >= 2*4*25*28) return;
    int j  = idx % 28;
    int r  = idx / 28;        // r = (dir*4+gate)*25 + k
    int k  = r % 25;
    int gk = r / 25;          // dir*4+gate
    int gate = gk & 3;
    const float* w = (gk >= 4) ? whh_b : whh_f;
    wpad[idx] = (j < 25) ? w[(gate*25 + k)*25 + j] : 0.f;
}

// ---- K1d: word Whh -> bf16 MFMA B-fragments.
//      Layout frag[dir][kc=4][nt=25][lane=64][e=8]; B[k][n] = Whh[n][k],
//      k = kc*32 + (lane>>4)*8 + e (zeros past k=100), n = nt*16 + (lane&15).
__global__ void k_wfrag(const float* __restrict__ whh_f, const float* __restrict__ whh_b,
                        __hip_bfloat16* __restrict__ frag) {
    int idx = blockIdx.x * blockDim.x + threadIdx.x;
    if (idx >= 2*4*25*64*8) return;
    int e  = idx & 7;
    int l  = (idx >> 3) & 63;
    int r  = idx >> 9;
    int nt = r % 25;
    int r2 = r / 25;
    int kc = r2 & 3;
    int d  = r2 >> 2;
    int k  = kc*32 + (l >> 4)*8 + e;
    int n  = nt*16 + (l & 15);
    const float* w = d ? whh_b : whh_f;
    float v = (k < 100) ? w[n*100 + k] : 0.f;
    frag[idx] = __float2bfloat16(v);
}

// ---- K2: char BiLSTM (scalar; MFMA port is next once k_wordm is proven).
__global__ __launch_bounds__(256)
__attribute__((amdgpu_waves_per_eu(2, 2)))
void k_char(
        const float* __restrict__ wpad, const float* __restrict__ gin,
        const int* __restrict__ char_ids, const int* __restrict__ word_num,
        float* __restrict__ wfbuf) {
    __shared__ __align__(16) float hsm[8][28];   // per-group h, padded 25->28
    __shared__ int chl[4][16];                   // per-word char ids
    int tid  = threadIdx.x;
    int grp  = tid >> 5, lane = tid & 31;
    int g    = blockIdx.x * 8 + grp;        // (word,dir) id: 0..65535
    int word = g >> 1, dir = g & 1;
    int b    = word >> 8, s = word & 255;
    int wd   = grp >> 1;                    // word slot in block: 0..3
    if (tid < 64) {
        int w = blockIdx.x * 4 + (tid >> 4);
        chl[tid >> 4][tid & 15] = char_ids[w*16 + (tid & 15)];
    }
    int k = (lane < 25) ? lane : 0;
    float4 w[4][7];
    const float* wp = wpad + ((size_t)dir*100 + k)*28;   // gate stride 25*28=700
#pragma unroll
    for (int gi = 0; gi < 4; ++gi)
#pragma unroll
        for (int j4 = 0; j4 < 7; ++j4)
            w[gi][j4] = *(const float4*)&wp[gi*700 + j4*4];
    if (lane < 28) hsm[grp][lane] = 0.f;
    __syncthreads();
    float h = 0.f, c = 0.f;
    const float* ginD = gin + dir*100*100;
    int t0 = dir ? 15 : 0;
    const float* gv = ginD + chl[wd][t0]*100;
    float ai = gv[k], af = gv[25 + k], ag = gv[50 + k], ao = gv[75 + k];
#pragma unroll 1
    for (int tt = 0; tt < 16; ++tt) {
        float bi = ai, bff = af, bg = ag, bo = ao;
        if (tt < 15) {
            int tn = dir ? (14 - tt) : (tt + 1);
            const float* gn = ginD + chl[wd][tn]*100;
            ai = gn[k]; af = gn[25 + k]; ag = gn[50 + k]; ao = gn[75 + k];
        }
        const float4* hp = (const float4*)hsm[grp];
#pragma unroll
        for (int j4 = 0; j4 < 7; ++j4) {
            float4 h4 = hp[j4];
            bi  += w[0][j4].x*h4.x + w[0][j4].y*h4.y + w[0][j4].z*h4.z + w[0][j4].w*h4.w;
            bff += w[1][j4].x*h4.x + w[1][j4].y*h4.y + w[1][j4].z*h4.z + w[1][j4].w*h4.w;
            bg  += w[2][j4].x*h4.x + w[2][j4].y*h4.y + w[2][j4].z*h4.z + w[2][j4].w*h4.w;
            bo  += w[3][j4].x*h4.x + w[3][j4].y*h4.y + w[3][j4].z*h4.z + w[3][j4].w*h4.w;
        }
        c = sigf(bff)*c + sigf(bi)*tanhfast(bg);
        h = sigf(bo)*tanhfast(c);
        if (lane < 25) hsm[grp][k] = h;
    }
    if (lane < 25) {
        float m = (s < word_num[b]) ? 1.f : 0.f;
        wfbuf[(size_t)word*152 + 100 + dir*25 + lane] = h * m;  // [hf | hb], masked
    }
}

// ---- K3a: gather word embeddings into wfbuf[:,0:100]; zero k-pad 150..151
__global__ void k_gather(const float* __restrict__ we, const int* __restrict__ wids,
                         float* __restrict__ wfbuf) {
    int idx = blockIdx.x * blockDim.x + threadIdx.x;
    if (idx >= TOK*152) return;
    int t = idx / 152, e = idx - t*152;
    if (e < 100)        wfbuf[idx] = we[(size_t)wids[t]*100 + e];
    else if (e >= 150)  wfbuf[idx] = 0.f;
}

// ---- K3b: word input gates GEMM  [32768,152] @ [152,800] -> bf16 gates [t][r]
__global__ __launch_bounds__(256) void k_gemm_in(
        const float* __restrict__ A, const float* __restrict__ Wc,
        const float* __restrict__ bc, __hip_bfloat16* __restrict__ gates) {
    __shared__ float As[8][64];
    __shared__ float Bs[8][64];
    int tid = threadIdx.x;
    int tileM = blockIdx.x & 511;
    int tileN = blockIdx.x >> 9;        // 0..12
    int m0 = tileM*64, n0 = tileN*64;
    int ty = tid >> 4, tx = tid & 15;
    int a_m = tid >> 2, a_k = (tid & 3)*2;
    float acc[4][4] = {};
    for (int k0 = 0; k0 < 152; k0 += 8) {
        float2 av = *(const float2*)&A[(size_t)(m0 + a_m)*152 + k0 + a_k];
        float2 bv = make_float2(0.f, 0.f);
        if (n0 + a_m < 800)
            bv = *(const float2*)&Wc[(size_t)(n0 + a_m)*152 + k0 + a_k];
        __syncthreads();
        As[a_k][a_m] = av.x; As[a_k+1][a_m] = av.y;
        Bs[a_k][a_m] = bv.x; Bs[a_k+1][a_m] = bv.y;
        __syncthreads();
#pragma unroll
        for (int kk = 0; kk < 8; ++kk) {
            float4 a4 = *(const float4*)&As[kk][ty*4];
            float4 b4 = *(const float4*)&Bs[kk][tx*4];
            float am[4] = {a4.x, a4.y, a4.z, a4.w};
            float bn[4] = {b4.x, b4.y, b4.z, b4.w};
#pragma unroll
            for (int p = 0; p < 4; ++p)
#pragma unroll
                for (int q = 0; q < 4; ++q) acc[p][q] += am[p]*bn[q];
        }
    }
#pragma unroll
    for (int p = 0; p < 4; ++p) {
        int m = m0 + ty*4 + p;
#pragma unroll
        for (int q = 0; q < 4; ++q) {
            int n = n0 + tx*4 + q;
            if (n < 800) {
                int dir = n >= 400 ? 1 : 0, r = n - dir*400;
                gates[((size_t)dir*TOK + m)*400 + r] = __float2bfloat16(acc[p][q] + bc[n]);
            }
        }
    }
}

// ---- K4: word BiLSTM on MFMA. 16 blocks = (btile 0..7)×dir, 256 thr = 4 waves.
//      Per step: C[16,400] = [H_hi|H_lo][16,128] @ Wfrag (56 mfma/wave, n-split
//      across waves) -> C_lds -> pointwise LSTM by 1600 unit-slots -> h hi/lo
//      back to H_lds. h carried as bf16 hi+lo (~f32 accuracy); W bf16 (same
//      error class as the bf16 gates which already pass). Gates prefetched one
//      step ahead. Scalar-FMA version was VALU-issue-bound at 3x useful work
//      (VGPR_Count 88 proved weights never resident).
__global__ __launch_bounds__(256, 1)
void k_wordm(
        const __hip_bfloat16* __restrict__ gates,
        const __hip_bfloat16* __restrict__ frag,
        __hip_bfloat16* __restrict__ wh) {
    __shared__ __bf16 Hl[2][16][136];     // h hi/lo planes, k-padded 128->136
    __shared__ float  Cl[16][404];        // recurrent gate pre-acts
    int bt  = blockIdx.x >> 1, dir = blockIdx.x & 1;
    int b0  = bt * 16;
    int tid = threadIdx.x;
    int wv  = tid >> 6;
    int lane = tid & 63;
    int lm  = lane & 15;       // A row / C col
    int lg  = lane >> 4;       // k-subgroup / C row group
    // zero H (incl. pad)
    for (int i = tid; i < 2*16*136; i += 256) ((__bf16*)Hl)[i] = (__bf16)0.f;
    // B-fragments: wave wv owns n-tiles {wv, wv+4, ...}: 7 for wv0, 6 otherwise
    bf16x8 Bf[7][4];
    const __hip_bfloat16* fb = frag + (size_t)dir*(4*25*512);
#pragma unroll
    for (int j = 0; j < 7; ++j) {
        int nt = wv + 4*j;
#pragma unroll
        for (int kc = 0; kc < 4; ++kc) {
            bf16x8 v = {};
            if (nt < 25) v = *(const bf16x8*)&fb[(((size_t)kc*25 + nt)*64 + lane)*8];
            Bf[j][kc] = v;
        }
    }
    // activation slots: idx = tid + 256*j, 1600 = 16 rows x 100 units
    int   m_[7], u_[7];
    size_t gb_[7], wb_[7];
    int   cb_[7];
    float c_[7];
#pragma unroll
    for (int j = 0; j < 7; ++j) {
        int idx = tid + 256*j;
        int mm = idx / 100, uu = idx - mm*100;
        m_[j] = mm; u_[j] = uu; c_[j] = 0.f;
        gb_[j] = ((size_t)dir*TOK + (size_t)(b0 + mm)*256)*400 + uu;
        wb_[j] = ((size_t)(b0 + mm)*256)*200 + dir*100 + uu;
        cb_[j] = mm*404 + uu;
    }
    __syncthreads();
    // prologue: gates for step 0
    int t0 = dir ? 255 : 0;
    unsigned short Gc[7][4];
#pragma unroll
    for (int j = 0; j < 7; ++j) {
        unsigned short g0 = 0, g1 = 0, g2 = 0, g3 = 0;
        if (tid + 256*j < 1600) {
            const unsigned short* p = (const unsigned short*)gates + gb_[j] + (size_t)t0*400;
            g0 = p[0]; g1 = p[100]; g2 = p[200]; g3 = p[300];
        }
        Gc[j][0] = g0; Gc[j][1] = g1; Gc[j][2] = g2; Gc[j][3] = g3;
    }
    for (int tt = 0; tt < 256; ++tt) {
        int t = dir ? (255 - tt) : tt;
        // A-fragments from H (h_{t-1})
        bf16x8 Ah[4], Al[4];
#pragma unroll
        for (int kc = 0; kc < 4; ++kc) {
            Ah[kc] = *(const bf16x8*)&Hl[0][lm][kc*32 + lg*8];
            Al[kc] = *(const bf16x8*)&Hl[1][lm][kc*32 + lg*8];
        }
        // 56 MFMA: acc[j] = (H_hi + H_lo) @ B[:,ntile j]
        f32x4 acc[7];
#pragma unroll
        for (int j = 0; j < 7; ++j) {
            f32x4 a = {};
#pragma unroll
            for (int kc = 0; kc < 4; ++kc) {
                a = __builtin_amdgcn_mfma_f32_16x16x32_bf16(Ah[kc], Bf[j][kc], a, 0, 0, 0);
                a = __builtin_amdgcn_mfma_f32_16x16x32_bf16(Al[kc], Bf[j][kc], a, 0, 0, 0);
            }
            acc[j] = a;
        }
        // C -> LDS (row=(lane>>4)*4+reg, col=nt*16+(lane&15); stride 404: 2-way max)
#pragma unroll
        for (int j = 0; j < 7; ++j) {
            int nt = wv + 4*j;
            if (nt < 25) {
#pragma unroll
                for (int r = 0; r < 4; ++r)
                    Cl[lg*4 + r][nt*16 + lm] = acc[j][r];
            }
        }
        // prefetch next step's gates (consumed next iteration; HBM latency hidden)
        unsigned short Gn[7][4];
        if (tt < 255) {
            int tn = dir ? (t - 1) : (t + 1);
#pragma unroll
            for (int j = 0; j < 7; ++j) {
                unsigned short g0 = 0, g1 = 0, g2 = 0, g3 = 0;
                if (tid + 256*j < 1600) {
                    const unsigned short* p = (const unsigned short*)gates + gb_[j] + (size_t)tn*400;
                    g0 = p[0]; g1 = p[100]; g2 = p[200]; g3 = p[300];
                }
                Gn[j][0] = g0; Gn[j][1] = g1; Gn[j][2] = g2; Gn[j][3] = g3;
            }
        }
        __syncthreads();
        // pointwise LSTM per unit-slot
#pragma unroll
        for (int j = 0; j < 7; ++j) {
            if (tid + 256*j < 1600) {
                float gI = Cl[m_[j]][u_[j]      ] + bf2f(Gc[j][0]);
                float gF = Cl[m_[j]][u_[j] + 100] + bf2f(Gc[j][1]);
                float gG = Cl[m_[j]][u_[j] + 200] + bf2f(Gc[j][2]);
                float gO = Cl[m_[j]][u_[j] + 300] + bf2f(Gc[j][3]);
                float c  = sigf(gF)*c_[j] + sigf(gI)*tanhfast(gG);
                float h  = sigf(gO)*tanhfast(c);
                c_[j] = c;
                __bf16 hh = (__bf16)h;
                __bf16 hl = (__bf16)(h - (float)hh);
                Hl[0][m_[j]][u_[j]] = hh;
                Hl[1][m_[j]][u_[j]] = hl;
                wh[wb_[j] + (size_t)t*200] = *(__hip_bfloat16*)&hh;
            }
        }
#pragma unroll
        for (int j = 0; j < 7; ++j) {
            Gc[j][0] = Gn[j][0]; Gc[j][1] = Gn[j][1];
            Gc[j][2] = Gn[j][2]; Gc[j][3] = Gn[j][3];
        }
        __syncthreads();
    }
}

// ---- K5: feats = (tanh(wh@W1^T+b1)@W2^T+b2)*mask ; 32 tokens per block
__global__ __launch_bounds__(256) void k_feats(
        const __hip_bfloat16* __restrict__ wh,
        const float* __restrict__ W1, const float* __restrict__ b1,
        const float* __restrict__ W2, const float* __restrict__ b2,
        const int* __restrict__ word_num, float* __restrict__ feats) {
    __shared__ float As[8][32];
    __shared__ float Ws[8][100];
    __shared__ float mids[32][100];
    int tid = threadIdx.x;
    int m0  = blockIdx.x * 32;
    int a_m = tid >> 3, a_k = tid & 7;
    int tn  = tid % 25, tm = tid / 25;   // active: tid < 200
    float acc[4][4] = {};
    for (int k0 = 0; k0 < 200; k0 += 8) {
        float av = __bfloat162float(wh[(size_t)(m0 + a_m)*200 + k0 + a_k]);
        int i1 = tid + 256, i2 = tid + 512, i3 = tid + 768;
        float wv0 = W1[(tid>>3)*200 + k0 + (tid&7)];
        float wv1 = W1[(i1 >>3)*200 + k0 + (i1 &7)];
        float wv2 = W1[(i2 >>3)*200 + k0 + (i2 &7)];
        float wv3 = (i3 < 800) ? W1[(i3>>3)*200 + k0 + (i3&7)] : 0.f;
        __syncthreads();
        As[a_k][a_m] = av;
        Ws[tid&7][tid>>3] = wv0;
        Ws[i1 &7][i1 >>3] = wv1;
        Ws[i2 &7][i2 >>3] = wv2;
        if (i3 < 800) Ws[i3&7][i3>>3] = wv3;
        __syncthreads();
        if (tid < 200) {
#pragma unroll
            for (int kk = 0; kk < 8; ++kk) {
                float4 a4 = *(const float4*)&As[kk][tm*4];
                float4 w4 = *(const float4*)&Ws[kk][tn*4];
                float am[4] = {a4.x, a4.y, a4.z, a4.w};
                float wn[4] = {w4.x, w4.y, w4.z, w4.w};
#pragma unroll
                for (int p = 0; p < 4; ++p)
#pragma unroll
                    for (int q = 0; q < 4; ++q) acc[p][q] += am[p]*wn[q];
            }
        }
    }
    if (tid < 200) {
#pragma unroll
        for (int p = 0; p < 4; ++p)
#pragma unroll
            for (int q = 0; q < 4; ++q)
                mids[tm*4+p][tn*4+q] = tanhfast(acc[p][q] + b1[tn*4+q]);
    }
    __syncthreads();
    for (int idx = tid; idx < 288; idx += 256) {
        int tok = idx / 9, lab = idx - tok*9;
        int m = m0 + tok, bb = m >> 8, s = m & 255;
        float v = b2[lab];
        const float4* mp = (const float4*)mids[tok];
        const float4* wp = (const float4*)(W2 + lab*100);
#pragma unroll
        for (int k = 0; k < 25; ++k) {
            float4 mv = mp[k], wv = wp[k];
            v += mv.x*wv.x + mv.y*wv.y + mv.z*wv.z + mv.w*wv.w;
        }
        feats[(size_t)m*12 + lab] = (s < word_num[bb]) ? v : 0.f;
    }
}

// ---- K6: CRF numerator + log-forward recursion. One wave per batch row.
__global__ __launch_bounds__(64) void k_crf(
        const float* __restrict__ feats, const float* __restrict__ T,
        const int* __restrict__ word_num, const int* __restrict__ label_ids,
        float* __restrict__ perb) {
    int b = blockIdx.x, lane = threadIdx.x;
    int n = word_num[b];
    const int*   lab = label_ids + b*256;
    const float* fb  = feats + (size_t)b*256*12;
    float nm = 0.f;
    for (int t = lane; t < n; t += 64) {
        int lt = lab[t];
        int lp = (t == 0) ? 9 : lab[t-1];
        nm += fb[t*12 + lt] + T[lp*11 + lt];
    }
#pragma unroll
    for (int o = 32; o > 0; o >>= 1) nm += __shfl_down(nm, o, 64);
    nm = __shfl(nm, 0, 64);
    nm += T[lab[n-1]*11 + 10];
    int j = lane;
    float Tc[11];
#pragma unroll
    for (int i = 0; i < 11; ++i) Tc[i] = T[i*11 + (j < 11 ? j : 0)];
    float alpha = (j == 9) ? 0.f : -1000.f;
    for (int t = 0; t < n; ++t) {
        float obs = (j < 9) ? fb[t*12 + j] : -1000.f;
        float v[11], mx = -1e30f;
#pragma unroll
        for (int i = 0; i < 11; ++i) { v[i] = __shfl(alpha, i, 64) + Tc[i]; mx = fmaxf(mx, v[i]); }
        float ssum = 0.f;
#pragma unroll
        for (int i = 0; i < 11; ++i) ssum += __expf(v[i] - mx);
        alpha = obs + mx + __logf(ssum);
    }
    float vv[11], mx = -1e30f, ssum = 0.f;
#pragma unroll
    for (int i = 0; i < 11; ++i) { vv[i] = __shfl(alpha, i, 64) + Tc[i]; mx = fmaxf(mx, vv[i]); }
#pragma unroll
    for (int i = 0; i < 11; ++i) ssum += __expf(vv[i] - mx);
    float denom = __shfl(mx + __logf(ssum), 10, 64);
    if (lane == 0) perb[b] = denom - nm;
}

// ---- K7: mean over batch
__global__ void k_reduce(const float* __restrict__ perb, float* __restrict__ out) {
    int t = threadIdx.x;
    float v = perb[t];
#pragma unroll
    for (int o = 32; o > 0; o >>= 1) v += __shfl_down(v, o, 64);
    __shared__ float sm[2];
    if ((t & 63) == 0) sm[t >> 6] = v;
    __syncthreads();
    if (t == 0) out[0] = (sm[0] + sm[1]) * (1.0f/128.0f);
}

extern "C" void kernel_launch(void* const* d_in, const int* in_sizes, int n_in,
                              void* d_out, int out_size, void* d_ws, size_t ws_size,
                              hipStream_t stream) {
    const float* word_emb = (const float*)d_in[0];
    const float* char_emb = (const float*)d_in[1];
    const float* cWih_f   = (const float*)d_in[2];
    const float* cWhh_f   = (const float*)d_in[3];
    const float* cb_f     = (const float*)d_in[4];
    const float* cWih_b   = (const float*)d_in[5];
    const float* cWhh_b   = (const float*)d_in[6];
    const float* cb_b     = (const float*)d_in[7];
    const float* wWih_f   = (const float*)d_in[8];
    const float* wWhh_f   = (const float*)d_in[9];
    const float* wb_f     = (const float*)d_in[10];
    const float* wWih_b   = (const float*)d_in[11];
    const float* wWhh_b   = (const float*)d_in[12];
    const float* wb_b     = (const float*)d_in[13];
    const float* W1       = (const float*)d_in[14];
    const float* b1       = (const float*)d_in[15];
    const float* W2       = (const float*)d_in[16];
    const float* b2       = (const float*)d_in[17];
    const float* T        = (const float*)d_in[18];
    const int* word_num   = (const int*)d_in[19];
    const int* word_ids   = (const int*)d_in[20];
    const int* char_ids   = (const int*)d_in[21];
    const int* label_ids  = (const int*)d_in[22];

    char* ws = (char*)d_ws;
    float* gin            = (float*)(ws);                       //    80,000 B
    float* Wc             = (float*)(ws + 80000);               //   486,400 B
    float* bc             = (float*)(ws + 566400);              //     3,200 B
    float* wfbuf          = (float*)(ws + 569600);              // 19,922,944 B [32768][152]
    __hip_bfloat16* gates = (__hip_bfloat16*)(ws + 20492544);   // 52,428,800 B [2][32768][400]
    __hip_bfloat16* wh    = (__hip_bfloat16*)(ws + 72921344);   // 13,107,200 B [32768][200]
    float* feats          = (float*)(ws + 86028544);            //  1,572,864 B [32768][12]
    float* perb           = (float*)(ws + 87601408);            //       512 B
    // wpad (22,400 B) aliases head of `gates`: k_wpad -> k_char -> overwritten by
    // k_gemm_in (strictly serial on stream).
    float* wpad           = (float*)(ws + 20492544);
    // wfrag (204,800 B) aliases head of `feats`: k_wfrag -> k_wordm reads it ->
    // k_feats overwrites afterwards (strictly serial on stream).
    __hip_bfloat16* wfrag = (__hip_bfloat16*)(ws + 86028544);

    k_gin   <<<4, 64, 0, stream>>>(char_emb, cWih_f, cb_f, cWih_b, cb_b, gin);
    k_wcomb <<<(800*152 + 255)/256, 256, 0, stream>>>(wWih_f, wb_f, wWih_b, wb_b, Wc, bc);
    k_wpad  <<<(2*4*25*28 + 255)/256, 256, 0, stream>>>(cWhh_f, cWhh_b, wpad);
    k_wfrag <<<(2*4*25*64*8 + 255)/256, 256, 0, stream>>>(wWhh_f, wWhh_b, wfrag);
    k_gather<<<(TOK*152)/256, 256, 0, stream>>>(word_emb, word_ids, wfbuf);
    k_char  <<<8192, 256, 0, stream>>>(wpad, gin, char_ids, word_num, wfbuf);
    k_gemm_in<<<512*13, 256, 0, stream>>>(wfbuf, Wc, bc, gates);
    k_wordm <<<16, 256, 0, stream>>>(gates, wfrag, wh);
    k_feats <<<1024, 256, 0, stream>>>(wh, W1, b1, W2, b2, word_num, feats);
    k_crf   <<<128, 64, 0, stream>>>(feats, T, word_num, label_ids, perb);
    k_reduce<<<1, 128, 0, stream>>>(perb, (float*)d_out);
}

// Round 4
// 699.802 us; speedup vs baseline: 1.5412x; 1.5412x over previous
//
#include <hip/hip_runtime.h>
#include <hip/hip_bf16.h>
#include <cstdint>
#include <cstddef>

#define B_ 128
#define S_ 256
#define TOK (B_*S_)   // 32768

typedef _Float16 f16;
typedef _Float16 f16x2 __attribute__((ext_vector_type(2)));

__device__ __forceinline__ float sigf(float x) {
    return __builtin_amdgcn_rcpf(1.0f + __expf(-x));
}
__device__ __forceinline__ float tanhfast(float x) {
    return 1.0f - 2.0f * __builtin_amdgcn_rcpf(1.0f + __expf(2.0f * x));
}
__device__ __forceinline__ float bf2f(unsigned short v) {
    union { unsigned u; float f; } c; c.u = ((unsigned)v) << 16; return c.f;
}
// packed f16 dot2 with f32 accumulate: d = a.x*b.x + a.y*b.y + c (VOP3P)
__device__ __forceinline__ float dot2(f16x2 a, f16x2 b, float c) {
    float d;
    asm("v_dot2_f32_f16 %0, %1, %2, %3" : "=v"(d) : "v"(a), "v"(b), "v"(c));
    return d;
}
__device__ __forceinline__ f16x2 u2h2(uint32_t v) {
    union { uint32_t u; f16x2 h; } c; c.u = v; return c.h;
}

// ---- K1: char input-gate table: gin[dir][c][row] = b[row] + Wih[row,:]·emb[c,:]
__global__ void k_gin(const float* __restrict__ ce,
                      const float* __restrict__ wih_f, const float* __restrict__ b_f,
                      const float* __restrict__ wih_b, const float* __restrict__ b_b,
                      float* __restrict__ gin) {
    int tid = blockIdx.x * blockDim.x + threadIdx.x;
    if (tid >= 200) return;
    int dir = tid / 100, row = tid % 100;
    const float* wih = dir ? wih_b : wih_f;
    float bias = dir ? b_b[row] : b_f[row];
    for (int c = 0; c < 100; ++c) {
        float s = bias;
#pragma unroll
        for (int k = 0; k < 25; ++k) s += wih[row*25 + k] * ce[c*25 + k];
        gin[(dir*100 + c)*100 + row] = s;
    }
}

// ---- K1b: combined word-input weight [800][152] (k-padded) + bias [800]
__global__ void k_wcomb(const float* __restrict__ wih_f, const float* __restrict__ bf,
                        const float* __restrict__ wih_b, const float* __restrict__ bb,
                        float* __restrict__ Wc, float* __restrict__ bc) {
    int idx = blockIdx.x * blockDim.x + threadIdx.x;
    if (idx < 800*152) {
        int n = idx / 152, k = idx - n*152;
        int dir = n >= 400 ? 1 : 0, r = n - dir*400;
        const float* w = dir ? wih_b : wih_f;
        Wc[idx] = (k < 150) ? w[r*150 + k] : 0.0f;
    }
    if (idx < 800) {
        int dir = idx >= 400 ? 1 : 0, r = idx - dir*400;
        bc[idx] = dir ? bb[r] : bf[r];
    }
}

// ---- K1c: char Whh -> f16 table [dir*4+gate][unit=25][j-padded 26]
__global__ void k_wpad(const float* __restrict__ whh_f, const float* __restrict__ whh_b,
                       unsigned short* __restrict__ wpadh) {
    int idx = blockIdx.x * blockDim.x + threadIdx.x;
    if (idx >= 2*4*25*26) return;
    int j  = idx % 26;
    int r  = idx / 26;        // r = (dir*4+gate)*25 + u
    int u  = r % 25;
    int gk = r / 25;          // dir*4+gate
    int gate = gk & 3;
    const float* w = (gk >= 4) ? whh_b : whh_f;
    float v = (j < 25) ? w[(gate*25 + u)*25 + j] : 0.f;
    union { f16 h; unsigned short s; } c; c.h = (f16)v;
    wpadh[idx] = c.s;
}

// ---- K2: char BiLSTM. 8 groups of 32 lanes per block; h exchanged via LDS (f16).
//      v3: v_dot2_f32_f16 halves both issue count and weight footprint
//      (52 dwords/thread) -- the scalar-f32 version was VALU-issue-bound with
//      the 112-float weight array never arch-VGPR-resident.
__global__ __launch_bounds__(256)
__attribute__((amdgpu_waves_per_eu(2, 2)))
void k_char(
        const unsigned short* __restrict__ wpadh, const float* __restrict__ gin,
        const int* __restrict__ char_ids, const int* __restrict__ word_num,
        float* __restrict__ wfbuf) {
    __shared__ uint32_t hsm[8][16];              // f16x2 h, 13 dwords used + pad
    __shared__ int chl[4][16];                   // per-word char ids
    int tid  = threadIdx.x;
    int grp  = tid >> 5, lane = tid & 31;
    int g    = blockIdx.x * 8 + grp;        // (word,dir) id: 0..65535
    int word = g >> 1, dir = g & 1;
    int b    = word >> 8, s = word & 255;
    int wd   = grp >> 1;                    // word slot in block: 0..3
    if (tid < 64) {
        int w = blockIdx.x * 4 + (tid >> 4);
        chl[tid >> 4][tid & 15] = char_ids[w*16 + (tid & 15)];
    }
    int u = (lane < 25) ? lane : 0;
    // weights: w[gate][i] = f16x2 pair (j=2i, 2i+1); row stride 13 dwords
    f16x2 w[4][13];
    const uint32_t* wp32 = (const uint32_t*)wpadh;
#pragma unroll
    for (int gi = 0; gi < 4; ++gi)
#pragma unroll
        for (int i = 0; i < 13; ++i)
            w[gi][i] = u2h2(wp32[(((size_t)dir*4 + gi)*25 + u)*13 + i]);
    if (lane < 16) hsm[grp][lane] = 0;      // h0 = 0 incl. pad
    __syncthreads();                        // chl visible to all groups
    float h = 0.f, c = 0.f;
    const float* ginD = gin + dir*100*100;
    int t0 = dir ? 15 : 0;
    const float* gv = ginD + chl[wd][t0]*100;
    float ai = gv[u], af = gv[25 + u], ag = gv[50 + u], ao = gv[75 + u];
#pragma unroll 1
    for (int tt = 0; tt < 16; ++tt) {
        float bi = ai, bff = af, bg = ag, bo = ao;
        if (tt < 15) {
            int tn = dir ? (14 - tt) : (tt + 1);
            const float* gn = ginD + chl[wd][tn]*100;
            ai = gn[u]; af = gn[25 + u]; ag = gn[50 + u]; ao = gn[75 + u];
        }
        const uint32_t* hp = hsm[grp];
#pragma unroll
        for (int i = 0; i < 13; ++i) {
            f16x2 h2 = u2h2(hp[i]);   // same-addr broadcast within group (free)
            bi  = dot2(w[0][i], h2, bi);
            bff = dot2(w[1][i], h2, bff);
            bg  = dot2(w[2][i], h2, bg);
            bo  = dot2(w[3][i], h2, bo);
        }
        c = sigf(bff)*c + sigf(bi)*tanhfast(bg);
        h = sigf(bo)*tanhfast(c);
        if (lane < 25) {
            union { f16 hh; unsigned short us; } cv; cv.hh = (f16)h;
            ((unsigned short*)hsm[grp])[u] = cv.us;   // wave-synchronous DS pipe
        }
    }
    if (lane < 25) {
        float m = (s < word_num[b]) ? 1.f : 0.f;
        wfbuf[(size_t)word*152 + 100 + dir*25 + lane] = h * m;  // [hf | hb], masked
    }
}

// ---- K3a: gather word embeddings into wfbuf[:,0:100]; zero k-pad 150..151
__global__ void k_gather(const float* __restrict__ we, const int* __restrict__ wids,
                         float* __restrict__ wfbuf) {
    int idx = blockIdx.x * blockDim.x + threadIdx.x;
    if (idx >= TOK*152) return;
    int t = idx / 152, e = idx - t*152;
    if (e < 100)        wfbuf[idx] = we[(size_t)wids[t]*100 + e];
    else if (e >= 150)  wfbuf[idx] = 0.f;
}

// ---- K3b: word input gates GEMM  [32768,152] @ [152,800] -> bf16 gates [t][r]
__global__ __launch_bounds__(256) void k_gemm_in(
        const float* __restrict__ A, const float* __restrict__ Wc,
        const float* __restrict__ bc, __hip_bfloat16* __restrict__ gates) {
    __shared__ float As[8][64];
    __shared__ float Bs[8][64];
    int tid = threadIdx.x;
    int tileM = blockIdx.x & 511;
    int tileN = blockIdx.x >> 9;        // 0..12
    int m0 = tileM*64, n0 = tileN*64;
    int ty = tid >> 4, tx = tid & 15;
    int a_m = tid >> 2, a_k = (tid & 3)*2;
    float acc[4][4] = {};
    for (int k0 = 0; k0 < 152; k0 += 8) {
        float2 av = *(const float2*)&A[(size_t)(m0 + a_m)*152 + k0 + a_k];
        float2 bv = make_float2(0.f, 0.f);
        if (n0 + a_m < 800)
            bv = *(const float2*)&Wc[(size_t)(n0 + a_m)*152 + k0 + a_k];
        __syncthreads();
        As[a_k][a_m] = av.x; As[a_k+1][a_m] = av.y;
        Bs[a_k][a_m] = bv.x; Bs[a_k+1][a_m] = bv.y;
        __syncthreads();
#pragma unroll
        for (int kk = 0; kk < 8; ++kk) {
            float4 a4 = *(const float4*)&As[kk][ty*4];
            float4 b4 = *(const float4*)&Bs[kk][tx*4];
            float am[4] = {a4.x, a4.y, a4.z, a4.w};
            float bn[4] = {b4.x, b4.y, b4.z, b4.w};
#pragma unroll
            for (int p = 0; p < 4; ++p)
#pragma unroll
                for (int q = 0; q < 4; ++q) acc[p][q] += am[p]*bn[q];
        }
    }
#pragma unroll
    for (int p = 0; p < 4; ++p) {
        int m = m0 + ty*4 + p;
#pragma unroll
        for (int q = 0; q < 4; ++q) {
            int n = n0 + tx*4 + q;
            if (n < 800) {
                int dir = n >= 400 ? 1 : 0, r = n - dir*400;
                gates[((size_t)dir*TOK + m)*400 + r] = __float2bfloat16(acc[p][q] + bc[n]);
            }
        }
    }
}

// ---- K4: word BiLSTM. 256 blocks=(b,dir); 512 threads: thread owns all 4 gate
//      rows of unit u with a 4-way k-split (kq = lane>>4), f16x2 dot2 weights
//      (52 dwords/thread). 8 waves/block = 2 waves/SIMD. 1 barrier/step; gate
//      prefetch; double-buffered f16 h in LDS.
__global__ __launch_bounds__(512)
__attribute__((amdgpu_waves_per_eu(2, 2)))
void k_word(
        const __hip_bfloat16* __restrict__ gates,
        const float* __restrict__ whh_f, const float* __restrict__ whh_b,
        __hip_bfloat16* __restrict__ wh) {
    int b = blockIdx.x >> 1, dir = blockIdx.x & 1;
    int tid = threadIdx.x;
    int wv   = tid >> 6;            // wave 0..7
    int lane = tid & 63;
    int kq   = lane >> 4;           // k-quarter: f16x2 dword chunks 4*i+kq
    int u    = wv*16 + (lane & 15); // unit 0..127
    bool act = (u < 100);
    const float* whh = dir ? whh_b : whh_f;
    __shared__ uint32_t Hs[2][64];  // double-buffered f16x2 h, 50 dwords + pad
    for (int i = tid; i < 128; i += 512) ((uint32_t*)Hs)[i] = 0;
    // weights: W[gate][i] = f16x2 of Whh[gate*100+u][k=2d,2d+1], d=4i+kq (<50)
    f16x2 W[4][13];
#pragma unroll
    for (int gi = 0; gi < 4; ++gi)
#pragma unroll
        for (int i = 0; i < 13; ++i) {
            int d = 4*i + kq;
            f16x2 v = {};
            if (act && d < 50) {
                const float* r = &whh[(size_t)(gi*100 + u)*100 + 2*d];
                v.x = (f16)r[0]; v.y = (f16)r[1];
            }
            W[gi][i] = v;
        }
    float cst = 0.f;
    const unsigned short* gp = (const unsigned short*)gates
                             + (size_t)(dir*TOK + b*256)*400;   // [t][gate*100+u]
    __syncthreads();
    int t0 = dir ? 255 : 0;
    unsigned short G0 = 0, G1 = 0, G2 = 0, G3 = 0;
    if (act) {
        const unsigned short* p = gp + (size_t)t0*400 + u;
        G0 = p[0]; G1 = p[100]; G2 = p[200]; G3 = p[300];
    }
    for (int tt = 0; tt < 256; ++tt) {
        int t = dir ? (255 - tt) : tt;
        float gI = bf2f(G0), gF = bf2f(G1), gG = bf2f(G2), gO = bf2f(G3);
        if (tt < 255 && act) {
            int tn = dir ? (t - 1) : (t + 1);
            const unsigned short* p = gp + (size_t)tn*400 + u;
            G0 = p[0]; G1 = p[100]; G2 = p[200]; G3 = p[300];
        }
        const uint32_t* hp = Hs[tt & 1];
        float a0 = 0.f, a1 = 0.f, a2 = 0.f, a3 = 0.f;
#pragma unroll
        for (int i = 0; i < 13; ++i) {
            f16x2 h2 = u2h2(hp[4*i + kq]);  // same-addr broadcast per 16-lane group
            a0 = dot2(W[0][i], h2, a0);
            a1 = dot2(W[1][i], h2, a1);
            a2 = dot2(W[2][i], h2, a2);
            a3 = dot2(W[3][i], h2, a3);
        }
        a0 += __shfl_xor(a0, 16, 64); a0 += __shfl_xor(a0, 32, 64);
        a1 += __shfl_xor(a1, 16, 64); a1 += __shfl_xor(a1, 32, 64);
        a2 += __shfl_xor(a2, 16, 64); a2 += __shfl_xor(a2, 32, 64);
        a3 += __shfl_xor(a3, 16, 64); a3 += __shfl_xor(a3, 32, 64);
        gI += a0; gF += a1; gG += a2; gO += a3;
        cst = sigf(gF)*cst + sigf(gI)*tanhfast(gG);
        float h = sigf(gO)*tanhfast(cst);
        if (act && kq == 0) {
            union { f16 hh; unsigned short us; } cv; cv.hh = (f16)h;
            ((unsigned short*)Hs[(tt + 1) & 1])[u] = cv.us;
            wh[(size_t)(b*256 + t)*200 + dir*100 + u] = __float2bfloat16(h);
        }
        __syncthreads();
    }
}

// ---- K5: feats = (tanh(wh@W1^T+b1)@W2^T+b2)*mask ; 32 tokens per block
__global__ __launch_bounds__(256) void k_feats(
        const __hip_bfloat16* __restrict__ wh,
        const float* __restrict__ W1, const float* __restrict__ b1,
        const float* __restrict__ W2, const float* __restrict__ b2,
        const int* __restrict__ word_num, float* __restrict__ feats) {
    __shared__ float As[8][32];
    __shared__ float Ws[8][100];
    __shared__ float mids[32][100];
    int tid = threadIdx.x;
    int m0  = blockIdx.x * 32;
    int a_m = tid >> 3, a_k = tid & 7;
    int tn  = tid % 25, tm = tid / 25;   // active: tid < 200
    float acc[4][4] = {};
    for (int k0 = 0; k0 < 200; k0 += 8) {
        float av = __bfloat162float(wh[(size_t)(m0 + a_m)*200 + k0 + a_k]);
        int i1 = tid + 256, i2 = tid + 512, i3 = tid + 768;
        float wv0 = W1[(tid>>3)*200 + k0 + (tid&7)];
        float wv1 = W1[(i1 >>3)*200 + k0 + (i1 &7)];
        float wv2 = W1[(i2 >>3)*200 + k0 + (i2 &7)];
        float wv3 = (i3 < 800) ? W1[(i3>>3)*200 + k0 + (i3&7)] : 0.f;
        __syncthreads();
        As[a_k][a_m] = av;
        Ws[tid&7][tid>>3] = wv0;
        Ws[i1 &7][i1 >>3] = wv1;
        Ws[i2 &7][i2 >>3] = wv2;
        if (i3 < 800) Ws[i3&7][i3>>3] = wv3;
        __syncthreads();
        if (tid < 200) {
#pragma unroll
            for (int kk = 0; kk < 8; ++kk) {
                float4 a4 = *(const float4*)&As[kk][tm*4];
                float4 w4 = *(const float4*)&Ws[kk][tn*4];
                float am[4] = {a4.x, a4.y, a4.z, a4.w};
                float wn[4] = {w4.x, w4.y, w4.z, w4.w};
#pragma unroll
                for (int p = 0; p < 4; ++p)
#pragma unroll
                    for (int q = 0; q < 4; ++q) acc[p][q] += am[p]*wn[q];
            }
        }
    }
    if (tid < 200) {
#pragma unroll
        for (int p = 0; p < 4; ++p)
#pragma unroll
            for (int q = 0; q < 4; ++q)
                mids[tm*4+p][tn*4+q] = tanhfast(acc[p][q] + b1[tn*4+q]);
    }
    __syncthreads();
    for (int idx = tid; idx < 288; idx += 256) {
        int tok = idx / 9, lab = idx - tok*9;
        int m = m0 + tok, bb = m >> 8, s = m & 255;
        float v = b2[lab];
        const float4* mp = (const float4*)mids[tok];
        const float4* wp = (const float4*)(W2 + lab*100);
#pragma unroll
        for (int k = 0; k < 25; ++k) {
            float4 mv = mp[k], wv = wp[k];
            v += mv.x*wv.x + mv.y*wv.y + mv.z*wv.z + mv.w*wv.w;
        }
        feats[(size_t)m*12 + lab] = (s < word_num[bb]) ? v : 0.f;
    }
}

// ---- K6: CRF numerator + log-forward recursion. One wave per batch row.
__global__ __launch_bounds__(64) void k_crf(
        const float* __restrict__ feats, const float* __restrict__ T,
        const int* __restrict__ word_num, const int* __restrict__ label_ids,
        float* __restrict__ perb) {
    int b = blockIdx.x, lane = threadIdx.x;
    int n = word_num[b];
    const int*   lab = label_ids + b*256;
    const float* fb  = feats + (size_t)b*256*12;
    float nm = 0.f;
    for (int t = lane; t < n; t += 64) {
        int lt = lab[t];
        int lp = (t == 0) ? 9 : lab[t-1];
        nm += fb[t*12 + lt] + T[lp*11 + lt];
    }
#pragma unroll
    for (int o = 32; o > 0; o >>= 1) nm += __shfl_down(nm, o, 64);
    nm = __shfl(nm, 0, 64);
    nm += T[lab[n-1]*11 + 10];
    int j = lane;
    float Tc[11];
#pragma unroll
    for (int i = 0; i < 11; ++i) Tc[i] = T[i*11 + (j < 11 ? j : 0)];
    float alpha = (j == 9) ? 0.f : -1000.f;
    for (int t = 0; t < n; ++t) {
        float obs = (j < 9) ? fb[t*12 + j] : -1000.f;
        float v[11], mx = -1e30f;
#pragma unroll
        for (int i = 0; i < 11; ++i) { v[i] = __shfl(alpha, i, 64) + Tc[i]; mx = fmaxf(mx, v[i]); }
        float ssum = 0.f;
#pragma unroll
        for (int i = 0; i < 11; ++i) ssum += __expf(v[i] - mx);
        alpha = obs + mx + __logf(ssum);
    }
    float vv[11], mx = -1e30f, ssum = 0.f;
#pragma unroll
    for (int i = 0; i < 11; ++i) { vv[i] = __shfl(alpha, i, 64) + Tc[i]; mx = fmaxf(mx, vv[i]); }
#pragma unroll
    for (int i = 0; i < 11; ++i) ssum += __expf(vv[i] - mx);
    float denom = __shfl(mx + __logf(ssum), 10, 64);
    if (lane == 0) perb[b] = denom - nm;
}

// ---- K7: mean over batch
__global__ void k_reduce(const float* __restrict__ perb, float* __restrict__ out) {
    int t = threadIdx.x;
    float v = perb[t];
#pragma unroll
    for (int o = 32; o > 0; o >>= 1) v += __shfl_down(v, o, 64);
    __shared__ float sm[2];
    if ((t & 63) == 0) sm[t >> 6] = v;
    __syncthreads();
    if (t == 0) out[0] = (sm[0] + sm[1]) * (1.0f/128.0f);
}

extern "C" void kernel_launch(void* const* d_in, const int* in_sizes, int n_in,
                              void* d_out, int out_size, void* d_ws, size_t ws_size,
                              hipStream_t stream) {
    const float* word_emb = (const float*)d_in[0];
    const float* char_emb = (const float*)d_in[1];
    const float* cWih_f   = (const float*)d_in[2];
    const float* cWhh_f   = (const float*)d_in[3];
    const float* cb_f     = (const float*)d_in[4];
    const float* cWih_b   = (const float*)d_in[5];
    const float* cWhh_b   = (const float*)d_in[6];
    const float* cb_b     = (const float*)d_in[7];
    const float* wWih_f   = (const float*)d_in[8];
    const float* wWhh_f   = (const float*)d_in[9];
    const float* wb_f     = (const float*)d_in[10];
    const float* wWih_b   = (const float*)d_in[11];
    const float* wWhh_b   = (const float*)d_in[12];
    const float* wb_b     = (const float*)d_in[13];
    const float* W1       = (const float*)d_in[14];
    const float* b1       = (const float*)d_in[15];
    const float* W2       = (const float*)d_in[16];
    const float* b2       = (const float*)d_in[17];
    const float* T        = (const float*)d_in[18];
    const int* word_num   = (const int*)d_in[19];
    const int* word_ids   = (const int*)d_in[20];
    const int* char_ids   = (const int*)d_in[21];
    const int* label_ids  = (const int*)d_in[22];

    char* ws = (char*)d_ws;
    float* gin            = (float*)(ws);                       //    80,000 B
    float* Wc             = (float*)(ws + 80000);               //   486,400 B
    float* bc             = (float*)(ws + 566400);              //     3,200 B
    float* wfbuf          = (float*)(ws + 569600);              // 19,922,944 B [32768][152]
    __hip_bfloat16* gates = (__hip_bfloat16*)(ws + 20492544);   // 52,428,800 B [2][32768][400]
    __hip_bfloat16* wh    = (__hip_bfloat16*)(ws + 72921344);   // 13,107,200 B [32768][200]
    float* feats          = (float*)(ws + 86028544);            //  1,572,864 B [32768][12]
    float* perb           = (float*)(ws + 87601408);            //       512 B
    // wpadh (10,400 B, f16) aliases head of `gates`: k_wpad -> k_char ->
    // overwritten by k_gemm_in (strictly serial on stream).
    unsigned short* wpadh = (unsigned short*)(ws + 20492544);

    k_gin   <<<4, 64, 0, stream>>>(char_emb, cWih_f, cb_f, cWih_b, cb_b, gin);
    k_wcomb <<<(800*152 + 255)/256, 256, 0, stream>>>(wWih_f, wb_f, wWih_b, wb_b, Wc, bc);
    k_wpad  <<<(2*4*25*26 + 255)/256, 256, 0, stream>>>(cWhh_f, cWhh_b, wpadh);
    k_gather<<<(TOK*152)/256, 256, 0, stream>>>(word_emb, word_ids, wfbuf);
    k_char  <<<8192, 256, 0, stream>>>(wpadh, gin, char_ids, word_num, wfbuf);
    k_gemm_in<<<512*13, 256, 0, stream>>>(wfbuf, Wc, bc, gates);
    k_word  <<<256, 512, 0, stream>>>(gates, wWhh_f, wWhh_b, wh);
    k_feats <<<1024, 256, 0, stream>>>(wh, W1, b1, W2, b2, word_num, feats);
    k_crf   <<<128, 64, 0, stream>>>(feats, T, word_num, label_ids, perb);
    k_reduce<<<1, 128, 0, stream>>>(perb, (float*)d_out);
}